// Round 4
// baseline (324.641 us; speedup 1.0000x reference)
//
#include <hip/hip_runtime.h>
#include <float.h>

// Problem constants (fixed by the reference): B=2, N=M=8192, G=256
#define B_ 2
#define N_ 8192
#define G_ 256
// CELL = abs(2*(-35)/256) = 70/256 = 0.2734375 exactly representable in fp32
constexpr float X_MIN_F = -35.0f;
constexpr float CELL_F  = 0.2734375f;

using u64 = unsigned long long;

// Workspace layout (bytes):
//   grid   i32[B*G*G]   [0, 524288)      packed (n<<1)|label, -1 invalid
//   accum  32B          [524288, 524320) {f32 sum, i32 cnt, u32 ticket, pad,
//                                         u32 ctr0, u32 ctr1, pad, pad}
//   px     u64[CC][B*N] [524320+, ...)   per-chunk packed (distbits<<32)|idx
//   py     f32[CC][B*N] after px         per-chunk min dist (y-direction)
#define OFF_ACCUM 524288
#define OFF_PX    524352

// ---------------------------------------------------------------------------
// Device-scope grid barrier (all gridDim.x blocks co-resident by construction:
// __launch_bounds__(256,4) -> VGPR<=128 -> 4 blocks/CU * 256 CUs = 1024).
// Release: threadfence before arrive; acquire: threadfence after spin.
// ---------------------------------------------------------------------------
__device__ __forceinline__ void grid_barrier(unsigned* ctr, unsigned target)
{
    __syncthreads();
    if (threadIdx.x == 0) {
        __threadfence();                      // release all prior writes
        atomicAdd(ctr, 1u);
        while (__hip_atomic_load(ctr, __ATOMIC_RELAXED,
                                 __HIP_MEMORY_SCOPE_AGENT) < target)
            __builtin_amdgcn_s_sleep(1);
        __threadfence();                      // acquire
    }
    __syncthreads();
}

// ---------------------------------------------------------------------------
// One persistent kernel, three phases separated by grid barriers.
//  Phase A (all blocks): 1-NN L1 split-K partials (no atomics) + grid=-1 init.
//    block -> (x=row-block of 1024 rows, y=column chunk, z=dir*2+b).
//    dir 0: p_i vs p_j with argmin (first occurrence); dir 1: p_j vs p_i,
//    min-dist only (reference discards that argmin).
//  Phase B (blocks 0..255): cross-chunk reduce (4 threads/point via LDS
//    atomicMin) + label + scatter atomicMax((n<<1)|label) into grid.
//  Phase C (all blocks): CE over valid cells + ticket finalize -> out[0].
// ---------------------------------------------------------------------------
template<int CC>
__global__ __launch_bounds__(256, 4) void mega_kernel(
    const float* __restrict__ p_i, const float* __restrict__ p_j,
    const float* __restrict__ mos, const float* __restrict__ flow,
    const int* __restrict__ nflow, int* __restrict__ grid,
    float* __restrict__ accum, u64* __restrict__ px, float* __restrict__ py,
    float* __restrict__ out)
{
    constexpr int COLS = N_ / CC;             // columns per chunk
    constexpr int NB   = 32 * CC;             // total blocks
    constexpr int LOG  = (CC == 32) ? 5 : 3;  // log2(CC)
    const int bid = blockIdx.x;
    const int tid = threadIdx.x;

    __shared__ __align__(16) float q[COLS * 3];

    // ---- Phase A: nn partials + grid init -------------------------------
    {
        const int x   = bid & 7;
        const int y   = (bid >> 3) & (CC - 1);
        const int dir = (bid >> (3 + LOG)) >> 1;
        const int b   = (bid >> (3 + LOG)) & 1;
        const int row0 = x * 1024 + tid * 4;
        const int c0   = y * COLS;

        const float* __restrict__ P = dir ? p_j : p_i;
        const float* __restrict__ Q = dir ? p_i : p_j;

        for (int t = tid; t < COLS * 3 / 4; t += 256)
            ((float4*)q)[t] = ((const float4*)(Q + ((size_t)b * N_ + c0) * 3))[t];

        // grid = -1 init, spread over all blocks (consumed only after barrier)
        constexpr int PER = 32768 / NB;       // uint4 per block (512KB total)
        if (tid < PER)
            ((uint4*)grid)[bid * PER + tid] = make_uint4(~0u, ~0u, ~0u, ~0u);

        // 4 consecutive rows = 12 consecutive floats = 3 float4
        const float4* pp = (const float4*)(P + ((size_t)b * N_ + row0) * 3);
        float4 r0 = pp[0], r1 = pp[1], r2 = pp[2];
        float px_[4] = {r0.x, r0.w, r1.z, r2.y};
        float py_[4] = {r0.y, r1.x, r1.w, r2.z};
        float pz_[4] = {r0.z, r1.y, r2.x, r2.w};

        float best[4]; int bidx[4];
#pragma unroll
        for (int r = 0; r < 4; r++) { best[r] = FLT_MAX; bidx[r] = c0; }

        __syncthreads();

        if (dir == 0) {
            for (int j4 = 0; j4 < COLS; j4 += 4) {
                float4 a  = *(const float4*)&q[j4 * 3];
                float4 bb = *(const float4*)&q[j4 * 3 + 4];
                float4 cc = *(const float4*)&q[j4 * 3 + 8];
                float qx[4] = {a.x, a.w, bb.z, cc.y};
                float qy[4] = {a.y, bb.x, bb.w, cc.z};
                float qz[4] = {a.z, bb.y, cc.x, cc.w};
#pragma unroll
                for (int k = 0; k < 4; k++) {
                    int jj = c0 + j4 + k;
#pragma unroll
                    for (int r = 0; r < 4; r++) {
                        // bit-match ref: (|d0| + |d1|) + |d2|, left-assoc fp32
                        float d = (fabsf(px_[r] - qx[k]) + fabsf(py_[r] - qy[k]))
                                  + fabsf(pz_[r] - qz[k]);
                        bool lt = d < best[r];   // strict < -> first occurrence
                        best[r] = lt ? d : best[r];
                        bidx[r] = lt ? jj : bidx[r];
                    }
                }
            }
            const size_t o = (size_t)y * (B_ * N_) + b * N_ + row0;
#pragma unroll
            for (int r = 0; r < 4; r++)
                // non-negative fp32 bits order like unsigned; idx in low bits
                // -> u64 min over chunks = (min dist, then min idx) = first occ
                px[o + r] = ((u64)__float_as_uint(best[r]) << 32) | (unsigned)bidx[r];
        } else {
            for (int j4 = 0; j4 < COLS; j4 += 4) {
                float4 a  = *(const float4*)&q[j4 * 3];
                float4 bb = *(const float4*)&q[j4 * 3 + 4];
                float4 cc = *(const float4*)&q[j4 * 3 + 8];
                float qx[4] = {a.x, a.w, bb.z, cc.y};
                float qy[4] = {a.y, bb.x, bb.w, cc.z};
                float qz[4] = {a.z, bb.y, cc.x, cc.w};
#pragma unroll
                for (int k = 0; k < 4; k++)
#pragma unroll
                    for (int r = 0; r < 4; r++) {
                        float d = (fabsf(px_[r] - qx[k]) + fabsf(py_[r] - qy[k]))
                                  + fabsf(pz_[r] - qz[k]);
                        best[r] = fminf(best[r], d);
                    }
            }
            const size_t o = (size_t)y * (B_ * N_) + b * N_ + row0;
#pragma unroll
            for (int r = 0; r < 4; r++) py[o + r] = best[r];
        }
    }

    grid_barrier((unsigned*)accum + 4, NB);

    // ---- Phase B: cross-chunk reduce + scatter (blocks 0..255) ----------
    if (bid < 256) {
        u64*      sbx = (u64*)q;              // 64 * 8B  = q[0..127]
        unsigned* sby = (unsigned*)(q + 128); // 64 * 4B  = q[128..191]
        const int p = tid & 63;               // point within block's batch
        const int g = tid >> 6;               // chunk group 0..3
        constexpr int CPG = CC / 4;           // chunks per group

        if (tid < 64) { sbx[tid] = ~0ull; sby[tid] = ~0u; }
        __syncthreads();

        const int pt = bid * 64 + p;          // in [0, B*N)
        u64   bx = ~0ull;
        float by = FLT_MAX;
#pragma unroll
        for (int k = 0; k < CPG; k++) {
            int c = g * CPG + k;
            u64 v = px[(size_t)c * (B_ * N_) + pt];
            bx = v < bx ? v : bx;
            by = fminf(by, py[(size_t)c * (B_ * N_) + pt]);
        }
        atomicMin(&sbx[p], bx);
        atomicMin(&sby[p], __float_as_uint(by));
        __syncthreads();

        if (tid < 64) {
            u64 fx = sbx[tid];
            float dx = __uint_as_float((unsigned)(fx >> 32));
            float dy = __uint_as_float(sby[tid]);
            float rigid = (dx + dy) * 0.5f;

            const int i = bid * 64 + tid;
            const int b = i >> 13;            // N = 8192
            const int n = i & (N_ - 1);

            bool dyn  = flow[i] > rigid;
            int label = dyn ? 1 : 0;
            int idx   = dyn ? nflow[i] : (int)(unsigned)(fx & 0xFFFFFFFFull);

            const float* qp = p_j + ((size_t)b * N_ + idx) * 3;
            float xx = qp[0], yy = qp[1];

            // bit-match ref: (p - shift) / CELL, IEEE fp32 divide, trunc cast
            int cx = (int)((xx - X_MIN_F) / CELL_F);
            int cy = (int)((yy - X_MIN_F) / CELL_F);

            // last-write-wins in point order n == max n wins
            atomicMax(&grid[(b << 16) + cx * G_ + cy], (n << 1) | label);
        }
    }

    grid_barrier((unsigned*)accum + 5, NB);

    // ---- Phase C: cross-entropy + ticket finalize -----------------------
    {
        int i = bid * 256 + tid;              // [0, NB*256); items: 131072
        float lsum = 0.0f;
        int   lcnt = 0;

        if (i < B_ * G_ * G_) {
            int packed = grid[i];
            if (packed >= 0) {
                int b    = i >> 16;           // G*G = 65536
                int cell = i & 0xFFFF;
                float m0 = mos[((size_t)b * 2 + 0) * 65536 + cell];
                float m1 = mos[((size_t)b * 2 + 1) * 65536 + cell];
                float mx = fmaxf(m0, m1);
                float lse = logf(expf(m0 - mx) + expf(m1 - mx));
                float sh  = ((packed & 1) ? m1 : m0) - mx;  // stable log_softmax
                lsum = sh - lse;
                lcnt = 1;
            }
        }

#pragma unroll
        for (int o = 32; o > 0; o >>= 1) {
            lsum += __shfl_down(lsum, o);
            lcnt += __shfl_down(lcnt, o);
        }
        __shared__ float wsum[4];
        __shared__ int   wcnt[4];
        __syncthreads();                      // q-overlay reuse from phase B
        int wave = tid >> 6;
        if ((tid & 63) == 0) { wsum[wave] = lsum; wcnt[wave] = lcnt; }
        __syncthreads();
        if (tid == 0) {
            float s = wsum[0] + wsum[1] + wsum[2] + wsum[3];
            int   c = wcnt[0] + wcnt[1] + wcnt[2] + wcnt[3];
            atomicAdd(&accum[0], s);
            atomicAdd((int*)&accum[1], c);
            __threadfence();
            unsigned t = atomicAdd((unsigned*)&accum[2], 1u);
            if (t == NB - 1) {
                float S = atomicAdd(&accum[0], 0.0f);
                int   C = atomicAdd((int*)&accum[1], 0);
                out[0] = -S / (float)(C > 0 ? C : 1);
            }
        }
    }
}

// ---------------------------------------------------------------------------
template<int CC>
static void run(const float* p_i, const float* mos, const float* p_j,
                const float* flow, const int* nflow, float* out,
                char* ws, hipStream_t stream)
{
    int*   grid  = (int*)ws;
    float* accum = (float*)(ws + OFF_ACCUM);
    u64*   px    = (u64*)(ws + OFF_PX);
    float* py    = (float*)(ws + OFF_PX + (size_t)CC * B_ * N_ * 8);

    // zero accum {sum, cnt, ticket, pad} + barrier counters {ctr0, ctr1}
    hipMemsetAsync(accum, 0, 32, stream);

    mega_kernel<CC><<<32 * CC, 256, 0, stream>>>(
        p_i, p_j, mos, flow, nflow, grid, accum, px, py, out);
}

extern "C" void kernel_launch(void* const* d_in, const int* in_sizes, int n_in,
                              void* d_out, int out_size, void* d_ws, size_t ws_size,
                              hipStream_t stream)
{
    const float* p_i   = (const float*)d_in[0];   // (B,N,3)
    const float* mos   = (const float*)d_in[1];   // (B,2,G,G)
    const float* p_j   = (const float*)d_in[2];   // (B,M,3)
    const float* flow  = (const float*)d_in[3];   // (B,N)
    const int*   nflow = (const int*)d_in[4];     // (B,N,1)
    float* out = (float*)d_out;
    char* ws = (char*)d_ws;

    // scratch: OFF_PX + CC*B*N*12 bytes. CC=32 -> ~6.8 MB, CC=8 -> ~2.1 MB
    if (ws_size >= OFF_PX + (size_t)32 * B_ * N_ * 12)
        run<32>(p_i, mos, p_j, flow, nflow, out, ws, stream);
    else
        run<8>(p_i, mos, p_j, flow, nflow, out, ws, stream);
}

// Round 5
// 137.535 us; speedup vs baseline: 2.3604x; 2.3604x over previous
//
#include <hip/hip_runtime.h>
#include <float.h>

// Problem constants (fixed by the reference): B=2, N=M=8192, G=256
#define B_ 2
#define N_ 8192
#define G_ 256
// CELL = abs(2*(-35)/256) = 70/256 = 0.2734375 exactly representable in fp32
constexpr float X_MIN_F = -35.0f;
constexpr float CELL_F  = 0.2734375f;

using u64 = unsigned long long;

// Workspace layout (bytes):
//   grid   i32[B*G*G]   [0, 524288)      packed (n<<1)|label, -1 invalid
//   accum  16B          [524288, 524304) {f32 sum, i32 cnt, u32 ticket, pad}
//   px     u64[CC][B*N] [524352, ...)    per-chunk packed (distbits<<32)|idx
//   py     f32[CC][B*N] after px         per-chunk min dist (y-direction)
#define OFF_ACCUM 524288
#define OFF_PX    524352

// ---------------------------------------------------------------------------
// 1-NN (L1), split-K over CC column chunks, NO atomics: each block writes its
// chunk-local best to px/py with plain coalesced stores. Also folds in the
// grid=-1 init and accum zeroing (consumed only after the kernel boundary).
//   grid: (8, CC, 4); z = dir*2 + b. dir 0: p_i vs p_j with argmin (first
//   occurrence); dir 1: p_j vs p_i, min-dist only (ref discards that argmin).
//   4 rows/thread register tiling; columns staged in LDS (tight xyz pack,
//   read back as float4 -> ds_read_b128 same-address broadcast).
// ---------------------------------------------------------------------------
template<int CC>
__global__ __launch_bounds__(256) void nn_kernel(const float* __restrict__ p_i,
                                                 const float* __restrict__ p_j,
                                                 u64* __restrict__ px,
                                                 float* __restrict__ py,
                                                 int* __restrict__ grid,
                                                 unsigned* __restrict__ accum)
{
    constexpr int COLS = N_ / CC;
    constexpr int NB   = 32 * CC;                // total blocks
    const int dir  = blockIdx.z >> 1;
    const int b    = blockIdx.z & 1;
    const int tid  = threadIdx.x;
    const int row0 = blockIdx.x * 1024 + tid * 4;
    const int c0   = blockIdx.y * COLS;

    const float* __restrict__ P = dir ? p_j : p_i;
    const float* __restrict__ Q = dir ? p_i : p_j;

    __shared__ __align__(16) float q[COLS * 3];
    for (int t = tid; t < COLS * 3 / 4; t += 256)
        ((float4*)q)[t] = ((const float4*)(Q + ((size_t)b * N_ + c0) * 3))[t];

    // folded init: grid = -1 (512 KB spread over all blocks), accum = 0
    {
        const int lin = blockIdx.x + 8 * (blockIdx.y + CC * blockIdx.z);
        constexpr int PER = 32768 / NB;          // uint4 per block
        if (tid < PER)
            ((uint4*)grid)[lin * PER + tid] = make_uint4(~0u, ~0u, ~0u, ~0u);
        if (lin == 0 && tid < 4) accum[tid] = 0u;
    }

    // 4 consecutive rows = 12 consecutive floats = 3 float4
    const float4* pp = (const float4*)(P + ((size_t)b * N_ + row0) * 3);
    float4 r0 = pp[0], r1 = pp[1], r2 = pp[2];
    float px_[4] = {r0.x, r0.w, r1.z, r2.y};
    float py_[4] = {r0.y, r1.x, r1.w, r2.z};
    float pz_[4] = {r0.z, r1.y, r2.x, r2.w};

    float best[4]; int bidx[4];
#pragma unroll
    for (int r = 0; r < 4; r++) { best[r] = FLT_MAX; bidx[r] = c0; }

    __syncthreads();

    if (dir == 0) {
        for (int j4 = 0; j4 < COLS; j4 += 4) {
            float4 a  = *(const float4*)&q[j4 * 3];
            float4 bb = *(const float4*)&q[j4 * 3 + 4];
            float4 cc = *(const float4*)&q[j4 * 3 + 8];
            float qx[4] = {a.x, a.w, bb.z, cc.y};
            float qy[4] = {a.y, bb.x, bb.w, cc.z};
            float qz[4] = {a.z, bb.y, cc.x, cc.w};
#pragma unroll
            for (int k = 0; k < 4; k++) {
                int jj = c0 + j4 + k;
#pragma unroll
                for (int r = 0; r < 4; r++) {
                    // bit-match reference: (|d0| + |d1|) + |d2|, left-assoc
                    float d = (fabsf(px_[r] - qx[k]) + fabsf(py_[r] - qy[k]))
                              + fabsf(pz_[r] - qz[k]);
                    bool lt = d < best[r];       // strict < -> first occurrence
                    best[r] = lt ? d : best[r];
                    bidx[r] = lt ? jj : bidx[r];
                }
            }
        }
        const size_t o = (size_t)blockIdx.y * (B_ * N_) + b * N_ + row0;
#pragma unroll
        for (int r = 0; r < 4; r++)
            // non-negative fp32 bits order like unsigned; idx in low bits ->
            // u64 min over chunks keeps (min dist, then min idx) = first occ.
            px[o + r] = ((u64)__float_as_uint(best[r]) << 32) | (unsigned)bidx[r];
    } else {
        for (int j4 = 0; j4 < COLS; j4 += 4) {
            float4 a  = *(const float4*)&q[j4 * 3];
            float4 bb = *(const float4*)&q[j4 * 3 + 4];
            float4 cc = *(const float4*)&q[j4 * 3 + 8];
            float qx[4] = {a.x, a.w, bb.z, cc.y};
            float qy[4] = {a.y, bb.x, bb.w, cc.z};
            float qz[4] = {a.z, bb.y, cc.x, cc.w};
#pragma unroll
            for (int k = 0; k < 4; k++)
#pragma unroll
                for (int r = 0; r < 4; r++) {
                    float d = (fabsf(px_[r] - qx[k]) + fabsf(py_[r] - qy[k]))
                              + fabsf(pz_[r] - qz[k]);
                    best[r] = fminf(best[r], d);
                }
        }
        const size_t o = (size_t)blockIdx.y * (B_ * N_) + b * N_ + row0;
#pragma unroll
        for (int r = 0; r < 4; r++) py[o + r] = best[r];
    }
}

// ---------------------------------------------------------------------------
// Cross-chunk reduce + label + scatter. 256 blocks x 256 threads: 4 threads
// per point (LDS atomicMin combine), 64 points per block -> 64K threads keep
// the 1M partial-loads latency-hidden (R3's 1-thread/pt version was the
// 35-40us latency bomb).
// Last-write-wins in point order n == max n wins -> atomicMax on packed
// (n<<1 | label); grid initialized to -1 by nn_kernel.
// ---------------------------------------------------------------------------
template<int CC>
__global__ __launch_bounds__(256) void reduce_scatter_kernel(
    const u64* __restrict__ px, const float* __restrict__ py,
    const float* __restrict__ flow, const int* __restrict__ nflow,
    const float* __restrict__ Pj, int* __restrict__ grid)
{
    __shared__ u64      sbx[64];
    __shared__ unsigned sby[64];
    const int tid = threadIdx.x;
    const int p   = tid & 63;                    // point within block
    const int g   = tid >> 6;                    // chunk group 0..3
    constexpr int CPG = CC / 4;                  // chunks per group

    if (tid < 64) { sbx[tid] = ~0ull; sby[tid] = ~0u; }
    __syncthreads();

    const int pt = blockIdx.x * 64 + p;          // in [0, B*N)
    u64   bx = ~0ull;
    float by = FLT_MAX;
#pragma unroll
    for (int k = 0; k < CPG; k++) {
        int c = g * CPG + k;
        u64 v = px[(size_t)c * (B_ * N_) + pt];
        bx = v < bx ? v : bx;
        by = fminf(by, py[(size_t)c * (B_ * N_) + pt]);
    }
    atomicMin(&sbx[p], bx);
    atomicMin(&sby[p], __float_as_uint(by));
    __syncthreads();

    if (tid < 64) {
        u64 fx = sbx[tid];
        float dx = __uint_as_float((unsigned)(fx >> 32));
        float dy = __uint_as_float(sby[tid]);
        float rigid = (dx + dy) * 0.5f;

        const int i = blockIdx.x * 64 + tid;
        const int b = i >> 13;                   // N = 8192
        const int n = i & (N_ - 1);

        bool dyn  = flow[i] > rigid;
        int label = dyn ? 1 : 0;
        int idx   = dyn ? nflow[i] : (int)(unsigned)(fx & 0xFFFFFFFFull);

        const float* qp = Pj + ((size_t)b * N_ + idx) * 3;
        float xx = qp[0], yy = qp[1];

        // bit-match ref: (p - shift) / CELL, IEEE fp32 divide, trunc cast
        int cx = (int)((xx - X_MIN_F) / CELL_F);
        int cy = (int)((yy - X_MIN_F) / CELL_F);

        atomicMax(&grid[(b << 16) + cx * G_ + cy], (n << 1) | label);
    }
}

// ---------------------------------------------------------------------------
// Cross-entropy over valid grid cells + fused finalize: last block (ticket)
// reads the device-scope accumulators and writes the loss.
// ---------------------------------------------------------------------------
__global__ __launch_bounds__(256) void ce_kernel(const float* __restrict__ mos,
                                                 const int* __restrict__ grid,
                                                 float* __restrict__ accum,
                                                 float* __restrict__ out)
{
    int i = blockIdx.x * 256 + threadIdx.x;      // i in [0, B*G*G) = 131072
    float lsum = 0.0f;
    int   lcnt = 0;

    int packed = grid[i];
    if (packed >= 0) {
        int b    = i >> 16;                      // G*G = 65536
        int cell = i & 0xFFFF;
        float m0 = mos[((size_t)b * 2 + 0) * 65536 + cell];
        float m1 = mos[((size_t)b * 2 + 1) * 65536 + cell];
        float mx = fmaxf(m0, m1);
        float lse = logf(expf(m0 - mx) + expf(m1 - mx));
        float sh  = ((packed & 1) ? m1 : m0) - mx;   // stable log_softmax
        lsum = sh - lse;
        lcnt = 1;
    }

    // wave-64 shuffle reduction
#pragma unroll
    for (int o = 32; o > 0; o >>= 1) {
        lsum += __shfl_down(lsum, o);
        lcnt += __shfl_down(lcnt, o);
    }
    __shared__ float wsum[4];
    __shared__ int   wcnt[4];
    int wave = threadIdx.x >> 6;
    if ((threadIdx.x & 63) == 0) { wsum[wave] = lsum; wcnt[wave] = lcnt; }
    __syncthreads();
    if (threadIdx.x == 0) {
        float s = wsum[0] + wsum[1] + wsum[2] + wsum[3];
        int   c = wcnt[0] + wcnt[1] + wcnt[2] + wcnt[3];
        atomicAdd(&accum[0], s);
        atomicAdd((int*)&accum[1], c);
        __threadfence();
        unsigned t = atomicAdd((unsigned*)&accum[2], 1u);
        if (t == gridDim.x - 1) {
            float S = atomicAdd(&accum[0], 0.0f);
            int   C = atomicAdd((int*)&accum[1], 0);
            out[0] = -S / (float)(C > 0 ? C : 1);
        }
    }
}

// ---------------------------------------------------------------------------
template<int CC>
static void run(const float* p_i, const float* mos, const float* p_j,
                const float* flow, const int* nflow, float* out,
                char* ws, hipStream_t stream)
{
    int*   grid  = (int*)ws;
    float* accum = (float*)(ws + OFF_ACCUM);
    u64*   px    = (u64*)(ws + OFF_PX);
    float* py    = (float*)(ws + OFF_PX + (size_t)CC * B_ * N_ * 8);

    dim3 g(8, CC, 4);
    nn_kernel<CC><<<g, 256, 0, stream>>>(p_i, p_j, px, py, (int*)grid,
                                         (unsigned*)accum);
    reduce_scatter_kernel<CC><<<256, 256, 0, stream>>>(px, py, flow, nflow,
                                                       p_j, grid);
    ce_kernel<<<(B_ * G_ * G_) / 256, 256, 0, stream>>>(mos, grid, accum, out);
}

extern "C" void kernel_launch(void* const* d_in, const int* in_sizes, int n_in,
                              void* d_out, int out_size, void* d_ws, size_t ws_size,
                              hipStream_t stream)
{
    const float* p_i   = (const float*)d_in[0];   // (B,N,3)
    const float* mos   = (const float*)d_in[1];   // (B,2,G,G)
    const float* p_j   = (const float*)d_in[2];   // (B,M,3)
    const float* flow  = (const float*)d_in[3];   // (B,N)
    const int*   nflow = (const int*)d_in[4];     // (B,N,1)
    float* out = (float*)d_out;
    char* ws = (char*)d_ws;

    // scratch: OFF_PX + CC*B*N*12 bytes. CC=32 -> ~6.8 MB, CC=8 -> ~2.1 MB
    if (ws_size >= OFF_PX + (size_t)32 * B_ * N_ * 12)
        run<32>(p_i, mos, p_j, flow, nflow, out, ws, stream);
    else
        run<8>(p_i, mos, p_j, flow, nflow, out, ws, stream);
}

// Round 6
// 128.395 us; speedup vs baseline: 2.5285x; 1.0712x over previous
//
#include <hip/hip_runtime.h>
#include <float.h>

// Problem constants (fixed by the reference): B=2, N=M=8192, G=256
#define B_ 2
#define N_ 8192
#define G_ 256
// CELL = abs(2*(-35)/256) = 70/256 = 0.2734375 exactly representable in fp32
constexpr float X_MIN_F = -35.0f;
constexpr float CELL_F  = 0.2734375f;

using u64 = unsigned long long;

// Workspace layout (bytes):
//   grid   i32[B*G*G]   [0, 524288)      packed (n<<1)|label, -1 invalid
//   accum  16B          [524288, 524304) {f32 sum, i32 cnt, u32 ticket, pad}
//   px     u64[CC][B*N] [524352, ...)    per-chunk packed (distbits<<32)|idx
//   py     f32[CC][B*N] after px         per-chunk min dist (y-direction)
#define OFF_ACCUM 524288
#define OFF_PX    524352

// ---------------------------------------------------------------------------
// 1-NN (L1), split-K over CC column chunks, NO atomics: each block writes its
// chunk-local best to px/py with plain coalesced stores. Grid=-1 init and
// accum zeroing folded in (consumed only after the kernel boundary).
//   grid: (8, CC, 4); z = dir*2 + b.
//   dir 0: p_i vs p_j WITH argmin — group-argmin scheme: min-tree over groups
//     of 8 columns (1 cmp + 2 cndmask per group instead of 3 ops/pair), then
//     an 8-column LDS rescan of the winning group recovers the exact column.
//     First-occurrence: strict < at group level keeps earliest group;
//     descending equality rescan keeps smallest k; packed-u64 min across
//     chunks keeps smallest idx on ties.
//   dir 1: p_j vs p_i, min-dist only (reference discards that argmin).
//   4 rows/thread; columns staged in LDS, read as float4 (ds_read_b128
//   same-address broadcast).
// ---------------------------------------------------------------------------
template<int CC>
__global__ __launch_bounds__(256) void nn_kernel(const float* __restrict__ p_i,
                                                 const float* __restrict__ p_j,
                                                 u64* __restrict__ px,
                                                 float* __restrict__ py,
                                                 int* __restrict__ grid,
                                                 unsigned* __restrict__ accum)
{
    constexpr int COLS = N_ / CC;
    constexpr int NB   = 32 * CC;                // total blocks
    const int dir  = blockIdx.z >> 1;
    const int b    = blockIdx.z & 1;
    const int tid  = threadIdx.x;
    const int row0 = blockIdx.x * 1024 + tid * 4;
    const int c0   = blockIdx.y * COLS;

    const float* __restrict__ P = dir ? p_j : p_i;
    const float* __restrict__ Q = dir ? p_i : p_j;

    __shared__ __align__(16) float q[COLS * 3];
    for (int t = tid; t < COLS * 3 / 4; t += 256)
        ((float4*)q)[t] = ((const float4*)(Q + ((size_t)b * N_ + c0) * 3))[t];

    // folded init: grid = -1 (512 KB spread over all blocks), accum = 0
    {
        const int lin = blockIdx.x + 8 * (blockIdx.y + CC * blockIdx.z);
        constexpr int PER = 32768 / NB;          // uint4 per block
        if (tid < PER)
            ((uint4*)grid)[lin * PER + tid] = make_uint4(~0u, ~0u, ~0u, ~0u);
        if (lin == 0 && tid < 4) accum[tid] = 0u;
    }

    // 4 consecutive rows = 12 consecutive floats = 3 float4
    const float4* pp = (const float4*)(P + ((size_t)b * N_ + row0) * 3);
    float4 r0 = pp[0], r1 = pp[1], r2 = pp[2];
    float px_[4] = {r0.x, r0.w, r1.z, r2.y};
    float py_[4] = {r0.y, r1.x, r1.w, r2.z};
    float pz_[4] = {r0.z, r1.y, r2.x, r2.w};

    float best[4];
#pragma unroll
    for (int r = 0; r < 4; r++) best[r] = FLT_MAX;

    __syncthreads();

    if (dir == 0) {
        int gcol[4] = {0, 0, 0, 0};              // winning group base (local)
        for (int jg = 0; jg < COLS; jg += 8) {
            const float4* qv = (const float4*)&q[jg * 3];
            float4 v0 = qv[0], v1 = qv[1], v2 = qv[2];
            float4 v3 = qv[3], v4 = qv[4], v5 = qv[5];
            float qx[8] = {v0.x, v0.w, v1.z, v2.y, v3.x, v3.w, v4.z, v5.y};
            float qy[8] = {v0.y, v1.x, v1.w, v2.z, v3.y, v4.x, v4.w, v5.z};
            float qz[8] = {v0.z, v1.y, v2.x, v2.w, v3.z, v4.y, v5.x, v5.w};
#pragma unroll
            for (int r = 0; r < 4; r++) {
                float d[8];
#pragma unroll
                for (int k = 0; k < 8; k++)
                    // bit-match reference: (|d0| + |d1|) + |d2|, left-assoc
                    d[k] = (fabsf(px_[r] - qx[k]) + fabsf(py_[r] - qy[k]))
                           + fabsf(pz_[r] - qz[k]);
                // min-tree (order-independent: min is assoc/comm, no NaN)
                float m01 = fminf(d[0], d[1]), m23 = fminf(d[2], d[3]);
                float m45 = fminf(d[4], d[5]), m67 = fminf(d[6], d[7]);
                float m = fminf(fminf(m01, m23), fminf(m45, m67));
                bool lt = m < best[r];           // strict < -> earliest group
                best[r] = lt ? m : best[r];
                gcol[r] = lt ? jg : gcol[r];
            }
        }
        // rescan winning group: recompute identical expressions, descending
        // equality overwrite -> smallest k = first occurrence.
        int bidx[4];
#pragma unroll
        for (int r = 0; r < 4; r++) {
            const float4* qv = (const float4*)&q[gcol[r] * 3];
            float4 v0 = qv[0], v1 = qv[1], v2 = qv[2];
            float4 v3 = qv[3], v4 = qv[4], v5 = qv[5];
            float qx[8] = {v0.x, v0.w, v1.z, v2.y, v3.x, v3.w, v4.z, v5.y};
            float qy[8] = {v0.y, v1.x, v1.w, v2.z, v3.y, v4.x, v4.w, v5.z};
            float qz[8] = {v0.z, v1.y, v2.x, v2.w, v3.z, v4.y, v5.x, v5.w};
            int kk = 0;
#pragma unroll
            for (int k = 7; k >= 0; k--) {
                float d = (fabsf(px_[r] - qx[k]) + fabsf(py_[r] - qy[k]))
                          + fabsf(pz_[r] - qz[k]);
                kk = (d == best[r]) ? k : kk;
            }
            bidx[r] = c0 + gcol[r] + kk;
        }
        const size_t o = (size_t)blockIdx.y * (B_ * N_) + b * N_ + row0;
#pragma unroll
        for (int r = 0; r < 4; r++)
            // non-negative fp32 bits order like unsigned; idx in low bits ->
            // u64 min over chunks keeps (min dist, then min idx) = first occ.
            px[o + r] = ((u64)__float_as_uint(best[r]) << 32) | (unsigned)bidx[r];
    } else {
        for (int jg = 0; jg < COLS; jg += 8) {
            const float4* qv = (const float4*)&q[jg * 3];
            float4 v0 = qv[0], v1 = qv[1], v2 = qv[2];
            float4 v3 = qv[3], v4 = qv[4], v5 = qv[5];
            float qx[8] = {v0.x, v0.w, v1.z, v2.y, v3.x, v3.w, v4.z, v5.y};
            float qy[8] = {v0.y, v1.x, v1.w, v2.z, v3.y, v4.x, v4.w, v5.z};
            float qz[8] = {v0.z, v1.y, v2.x, v2.w, v3.z, v4.y, v5.x, v5.w};
#pragma unroll
            for (int r = 0; r < 4; r++) {
#pragma unroll
                for (int k = 0; k < 8; k++) {
                    float d = (fabsf(px_[r] - qx[k]) + fabsf(py_[r] - qy[k]))
                              + fabsf(pz_[r] - qz[k]);
                    best[r] = fminf(best[r], d);
                }
            }
        }
        const size_t o = (size_t)blockIdx.y * (B_ * N_) + b * N_ + row0;
#pragma unroll
        for (int r = 0; r < 4; r++) py[o + r] = best[r];
    }
}

// ---------------------------------------------------------------------------
// Cross-chunk reduce + label + scatter. 256 blocks x 256 threads: 4 threads
// per point (LDS atomicMin combine), 64 points per block -> latency-hidden.
// Last-write-wins in point order n == max n wins -> atomicMax on packed
// (n<<1 | label); grid initialized to -1 by nn_kernel.
// ---------------------------------------------------------------------------
template<int CC>
__global__ __launch_bounds__(256) void reduce_scatter_kernel(
    const u64* __restrict__ px, const float* __restrict__ py,
    const float* __restrict__ flow, const int* __restrict__ nflow,
    const float* __restrict__ Pj, int* __restrict__ grid)
{
    __shared__ u64      sbx[64];
    __shared__ unsigned sby[64];
    const int tid = threadIdx.x;
    const int p   = tid & 63;                    // point within block
    const int g   = tid >> 6;                    // chunk group 0..3
    constexpr int CPG = CC / 4;                  // chunks per group

    if (tid < 64) { sbx[tid] = ~0ull; sby[tid] = ~0u; }
    __syncthreads();

    const int pt = blockIdx.x * 64 + p;          // in [0, B*N)
    u64   bx = ~0ull;
    float by = FLT_MAX;
#pragma unroll
    for (int k = 0; k < CPG; k++) {
        int c = g * CPG + k;
        u64 v = px[(size_t)c * (B_ * N_) + pt];
        bx = v < bx ? v : bx;
        by = fminf(by, py[(size_t)c * (B_ * N_) + pt]);
    }
    atomicMin(&sbx[p], bx);
    atomicMin(&sby[p], __float_as_uint(by));
    __syncthreads();

    if (tid < 64) {
        u64 fx = sbx[tid];
        float dx = __uint_as_float((unsigned)(fx >> 32));
        float dy = __uint_as_float(sby[tid]);
        float rigid = (dx + dy) * 0.5f;

        const int i = blockIdx.x * 64 + tid;
        const int b = i >> 13;                   // N = 8192
        const int n = i & (N_ - 1);

        bool dyn  = flow[i] > rigid;
        int label = dyn ? 1 : 0;
        int idx   = dyn ? nflow[i] : (int)(unsigned)(fx & 0xFFFFFFFFull);

        const float* qp = Pj + ((size_t)b * N_ + idx) * 3;
        float xx = qp[0], yy = qp[1];

        // bit-match ref: (p - shift) / CELL, IEEE fp32 divide, trunc cast
        int cx = (int)((xx - X_MIN_F) / CELL_F);
        int cy = (int)((yy - X_MIN_F) / CELL_F);

        atomicMax(&grid[(b << 16) + cx * G_ + cy], (n << 1) | label);
    }
}

// ---------------------------------------------------------------------------
// Cross-entropy over valid grid cells + fused finalize: last block (ticket)
// reads the device-scope accumulators and writes the loss.
// ---------------------------------------------------------------------------
__global__ __launch_bounds__(256) void ce_kernel(const float* __restrict__ mos,
                                                 const int* __restrict__ grid,
                                                 float* __restrict__ accum,
                                                 float* __restrict__ out)
{
    int i = blockIdx.x * 256 + threadIdx.x;      // i in [0, B*G*G) = 131072
    float lsum = 0.0f;
    int   lcnt = 0;

    int packed = grid[i];
    if (packed >= 0) {
        int b    = i >> 16;                      // G*G = 65536
        int cell = i & 0xFFFF;
        float m0 = mos[((size_t)b * 2 + 0) * 65536 + cell];
        float m1 = mos[((size_t)b * 2 + 1) * 65536 + cell];
        float mx = fmaxf(m0, m1);
        float lse = logf(expf(m0 - mx) + expf(m1 - mx));
        float sh  = ((packed & 1) ? m1 : m0) - mx;   // stable log_softmax
        lsum = sh - lse;
        lcnt = 1;
    }

    // wave-64 shuffle reduction
#pragma unroll
    for (int o = 32; o > 0; o >>= 1) {
        lsum += __shfl_down(lsum, o);
        lcnt += __shfl_down(lcnt, o);
    }
    __shared__ float wsum[4];
    __shared__ int   wcnt[4];
    int wave = threadIdx.x >> 6;
    if ((threadIdx.x & 63) == 0) { wsum[wave] = lsum; wcnt[wave] = lcnt; }
    __syncthreads();
    if (threadIdx.x == 0) {
        float s = wsum[0] + wsum[1] + wsum[2] + wsum[3];
        int   c = wcnt[0] + wcnt[1] + wcnt[2] + wcnt[3];
        atomicAdd(&accum[0], s);
        atomicAdd((int*)&accum[1], c);
        __threadfence();
        unsigned t = atomicAdd((unsigned*)&accum[2], 1u);
        if (t == gridDim.x - 1) {
            float S = atomicAdd(&accum[0], 0.0f);
            int   C = atomicAdd((int*)&accum[1], 0);
            out[0] = -S / (float)(C > 0 ? C : 1);
        }
    }
}

// ---------------------------------------------------------------------------
template<int CC>
static void run(const float* p_i, const float* mos, const float* p_j,
                const float* flow, const int* nflow, float* out,
                char* ws, hipStream_t stream)
{
    int*   grid  = (int*)ws;
    float* accum = (float*)(ws + OFF_ACCUM);
    u64*   px    = (u64*)(ws + OFF_PX);
    float* py    = (float*)(ws + OFF_PX + (size_t)CC * B_ * N_ * 8);

    dim3 g(8, CC, 4);
    nn_kernel<CC><<<g, 256, 0, stream>>>(p_i, p_j, px, py, (int*)grid,
                                         (unsigned*)accum);
    reduce_scatter_kernel<CC><<<256, 256, 0, stream>>>(px, py, flow, nflow,
                                                       p_j, grid);
    ce_kernel<<<(B_ * G_ * G_) / 256, 256, 0, stream>>>(mos, grid, accum, out);
}

extern "C" void kernel_launch(void* const* d_in, const int* in_sizes, int n_in,
                              void* d_out, int out_size, void* d_ws, size_t ws_size,
                              hipStream_t stream)
{
    const float* p_i   = (const float*)d_in[0];   // (B,N,3)
    const float* mos   = (const float*)d_in[1];   // (B,2,G,G)
    const float* p_j   = (const float*)d_in[2];   // (B,M,3)
    const float* flow  = (const float*)d_in[3];   // (B,N)
    const int*   nflow = (const int*)d_in[4];     // (B,N,1)
    float* out = (float*)d_out;
    char* ws = (char*)d_ws;

    // scratch: OFF_PX + CC*B*N*12 bytes. CC=64 -> ~13.1 MB, 32 -> ~7.3 MB,
    // 8 -> ~2.1 MB
    if (ws_size >= OFF_PX + (size_t)64 * B_ * N_ * 12)
        run<64>(p_i, mos, p_j, flow, nflow, out, ws, stream);
    else if (ws_size >= OFF_PX + (size_t)32 * B_ * N_ * 12)
        run<32>(p_i, mos, p_j, flow, nflow, out, ws, stream);
    else
        run<8>(p_i, mos, p_j, flow, nflow, out, ws, stream);
}